// Round 2
// baseline (444.857 us; speedup 1.0000x reference)
//
#include <hip/hip_runtime.h>

#define DIM 1024
#define SEQ 4096
#define MROWS 16384      // BATCH * SEQ
#define CHUNK 64
#define NCHUNKBLKS 256   // MROWS / CHUNK

typedef float  f32x4  __attribute__((ext_vector_type(4)));
typedef __bf16 bf16x8 __attribute__((ext_vector_type(8)));
typedef __bf16 bf16x4 __attribute__((ext_vector_type(4)));

// async global->LDS, 16B per lane. LDS dest is wave-uniform base + lane*16.
__device__ __forceinline__ void gld16(const void* g, void* l) {
  __builtin_amdgcn_global_load_lds((__attribute__((address_space(1))) void*)g,
                                   (__attribute__((address_space(3))) void*)l,
                                   16, 0, 0);
}

__device__ __forceinline__ f32x4 ld4f(const float* p) { return *(const f32x4*)p; }
__device__ __forceinline__ f32x4 ld4f(const __bf16* p) {
  bf16x4 v = *(const bf16x4*)p;
  f32x4 r;
#pragma unroll
  for (int j = 0; j < 4; ++j) r[j] = (float)v[j];
  return r;
}

// C[M,N] = A[M,DIM] (bf16) * Bt[N,DIM]^T (bf16) + bias, fp32 accumulate.
// MODE 0: out bf16 = acc + bias
// MODE 2: out f32  = base_phases[row%SEQ][col] + (acc+bias)*mod_scale
// MODE 4: out bf16 = base_phases[row%SEQ][col] + (acc+bias)*mod_scale
// MODE 3: out f32  = acc + bias + xres[row][col]   (final residual)
// Tile: 128x128 per block, 4 waves, each wave 64x64 = 4x4 frags of 16x16x32 MFMA.
template <int MODE>
__global__ __launch_bounds__(256, 2)
void gemm_bt(const __bf16* __restrict__ A, const __bf16* __restrict__ Bt,
             const float* __restrict__ bias, void* __restrict__ outp,
             const float* __restrict__ basep, const float* __restrict__ mscp,
             const float* __restrict__ xres)
{
  __shared__ __bf16 As[128 * 32];   // [m][k], 8 KB
  __shared__ __bf16 Bs[128 * 32];   // [n][k], 8 KB
  const int tid  = threadIdx.x;
  const int lane = tid & 63;
  const int widx = tid >> 6;
  const int wr   = widx >> 1, wc = widx & 1;
  const int row0 = blockIdx.y * 128, col0 = blockIdx.x * 128;

  // staging: lane l covers LDS bytes (widx*1024 + i*4096 + l*16)
  //  -> m = widx*16 + i*64 + (l>>2), k = (l&3)*8
  const __bf16* Ag = A  + (size_t)(row0 + widx * 16 + (lane >> 2)) * DIM + (lane & 3) * 8;
  const __bf16* Bg = Bt + (size_t)(col0 + widx * 16 + (lane >> 2)) * DIM + (lane & 3) * 8;
  char* AsL = (char*)As + widx * 1024;
  char* BsL = (char*)Bs + widx * 1024;

  f32x4 acc[4][4] = {};
  const bf16x8* Av = (const bf16x8*)As;
  const bf16x8* Bv = (const bf16x8*)Bs;
  const int ar = wr * 64 + (lane & 15);
  const int br = wc * 64 + (lane & 15);
  const int kg = lane >> 4;

  for (int kt = 0; kt < DIM / 32; ++kt) {
    const __bf16* a = Ag + kt * 32;
    const __bf16* b = Bg + kt * 32;
    gld16(a,            AsL);
    gld16(a + 64 * DIM, AsL + 4096);
    gld16(b,            BsL);
    gld16(b + 64 * DIM, BsL + 4096);
    __syncthreads();   // compiler emits vmcnt(0) drain before barrier
    bf16x8 af[4], bfv[4];
#pragma unroll
    for (int i = 0; i < 4; ++i) af[i]  = Av[(ar + i * 16) * 4 + kg];
#pragma unroll
    for (int i = 0; i < 4; ++i) bfv[i] = Bv[(br + i * 16) * 4 + kg];
#pragma unroll
    for (int mi = 0; mi < 4; ++mi)
#pragma unroll
      for (int ni = 0; ni < 4; ++ni)
        acc[mi][ni] = __builtin_amdgcn_mfma_f32_16x16x32_bf16(af[mi], bfv[ni], acc[mi][ni], 0, 0, 0);
    __syncthreads();
  }

  // C/D frag mapping (HW-verified): col = lane&15, row = (lane>>4)*4 + r
  const int ccol = col0 + wc * 64 + (lane & 15);
  const int crow = row0 + wr * 64 + kg * 4;
  float bvv[4];
#pragma unroll
  for (int ni = 0; ni < 4; ++ni) bvv[ni] = bias[ccol + ni * 16];
  float ms = 0.f;
  if (MODE == 2 || MODE == 4) ms = mscp[0];
#pragma unroll
  for (int mi = 0; mi < 4; ++mi) {
#pragma unroll
    for (int ni = 0; ni < 4; ++ni) {
#pragma unroll
      for (int r = 0; r < 4; ++r) {
        const int row = crow + mi * 16 + r;
        const int col = ccol + ni * 16;
        const size_t idx = (size_t)row * DIM + col;
        float v = acc[mi][ni][r] + bvv[ni];
        if (MODE == 0) {
          ((__bf16*)outp)[idx] = (__bf16)v;
        } else if (MODE == 2) {
          ((float*)outp)[idx] = basep[(size_t)(row & (SEQ - 1)) * DIM + col] + v * ms;
        } else if (MODE == 4) {
          ((__bf16*)outp)[idx] = (__bf16)(basep[(size_t)(row & (SEQ - 1)) * DIM + col] + v * ms);
        } else {
          ((float*)outp)[idx] = v + xres[idx];
        }
      }
    }
  }
}

// Per chunk (64 rows) x full D: bound = value*exp(i*kphase), in-chunk cumsum
// (registers, sequential over 64 rows), retrieve with qphase, /sqrt(D),
// LayerNorm per row (block reduction over 1024 cols), emit bf16 normed.
// One block per chunk: 256 blocks x 256 threads, thread t owns cols 4t..4t+3.
template <typename PT>
__global__ __launch_bounds__(256)
void phasor_ln(const __bf16* __restrict__ val, const PT* __restrict__ kph,
               const PT* __restrict__ qph, const float* __restrict__ g,
               const float* __restrict__ lb, __bf16* __restrict__ nb)
{
  const int t = threadIdx.x;
  const size_t r0 = (size_t)blockIdx.x * CHUNK;
  const int c = t * 4;
  const f32x4 gv  = ((const f32x4*)g)[t];
  const f32x4 lbv = ((const f32x4*)lb)[t];
  __shared__ float red[8];
  float mr[4] = {0.f, 0.f, 0.f, 0.f};
  float mi[4] = {0.f, 0.f, 0.f, 0.f};
  size_t base = r0 * DIM + c;
  f32x4 v  = ld4f(val + base);
  f32x4 kp = ld4f(kph + base);
  f32x4 qp = ld4f(qph + base);
  for (int r = 0; r < CHUNK; ++r) {
    // prefetch next row before the reduction chain (hide HBM latency)
    const size_t nbase = base + ((r + 1 < CHUNK) ? DIM : 0);
    f32x4 nv  = ld4f(val + nbase);
    f32x4 nkp = ld4f(kph + nbase);
    f32x4 nqp = ld4f(qph + nbase);
    float ret[4];
    float s = 0.f, q = 0.f;
#pragma unroll
    for (int j = 0; j < 4; ++j) {
      float sk, ck, sq, cq;
      __sincosf(kp[j], &sk, &ck);
      mr[j] += v[j] * ck;
      mi[j] += v[j] * sk;
      __sincosf(qp[j], &sq, &cq);
      ret[j] = (mr[j] * cq + mi[j] * sq) * 0.03125f;   // 1/sqrt(1024)
      s += ret[j];
      q += ret[j] * ret[j];
    }
#pragma unroll
    for (int off = 32; off > 0; off >>= 1) {
      s += __shfl_down(s, off);
      q += __shfl_down(q, off);
    }
    if ((t & 63) == 0) { red[t >> 6] = s; red[4 + (t >> 6)] = q; }
    __syncthreads();
    const float mu   = (red[0] + red[1] + red[2] + red[3]) * (1.0f / DIM);
    const float varr = (red[4] + red[5] + red[6] + red[7]) * (1.0f / DIM) - mu * mu;
    const float rinv = rsqrtf(varr + 1e-5f);
    bf16x4 o;
#pragma unroll
    for (int j = 0; j < 4; ++j) o[j] = (__bf16)((ret[j] - mu) * rinv * gv[j] + lbv[j]);
    *(bf16x4*)(nb + base) = o;
    __syncthreads();   // protect red[] before next row overwrites
    base += DIM;
    v = nv; kp = nkp; qp = nqp;
  }
}

// fp32 -> bf16, vectorized 4/thread
__global__ void f2b_kernel(const float* __restrict__ in, __bf16* __restrict__ out, int n4) {
  int i = blockIdx.x * 256 + threadIdx.x;
  if (i >= n4) return;
  f32x4 vv = ((const f32x4*)in)[i];
  bf16x4 o;
#pragma unroll
  for (int j = 0; j < 4; ++j) o[j] = (__bf16)vv[j];
  ((bf16x4*)out)[i] = o;
}

// Wt[n][k] = (bf16) W[k][n]; 32x32 LDS tile transpose
__global__ void transpose_f2b(const float* __restrict__ W, __bf16* __restrict__ Wt) {
  __shared__ float tle[32][33];
  const int tx = threadIdx.x, ty = threadIdx.y;
  const int bx = blockIdx.x * 32, by = blockIdx.y * 32;
  for (int i = ty; i < 32; i += 8) tle[i][tx] = W[(size_t)(by + i) * DIM + bx + tx];
  __syncthreads();
  for (int i = ty; i < 32; i += 8) Wt[(size_t)(bx + i) * DIM + by + tx] = (__bf16)tle[tx][i];
}

// diagnostic fallback: out = x (signals "workspace too small" as absmax ~6.5)
__global__ void copyx_kernel(const float* __restrict__ x, float* __restrict__ out, int n4) {
  int i = blockIdx.x * 256 + threadIdx.x;
  if (i >= n4) return;
  ((f32x4*)out)[i] = ((const f32x4*)x)[i];
}

template <typename PT, int PHMODE>
static void run_pipeline(const float* x, const float* basep,
                         const float* Wk, const float* bk, const float* Wv, const float* bv,
                         const float* Wq, const float* bq, const float* Wkm, const float* bkm,
                         const float* Wqm, const float* bqm, const float* msc,
                         const float* lng, const float* lnb, const float* Wo, const float* bo,
                         float* out,
                         __bf16* xb, __bf16* kb, __bf16* qb, __bf16* valb,
                         PT* kphs, PT* qphs, __bf16* Wbase, __bf16* nbuf,
                         hipStream_t stream)
{
  __bf16* WkT  = Wbase + 0 * 1024 * 1024;
  __bf16* WvT  = Wbase + 1 * 1024 * 1024;
  __bf16* WqT  = Wbase + 2 * 1024 * 1024;
  __bf16* WkmT = Wbase + 3 * 1024 * 1024;
  __bf16* WqmT = Wbase + 4 * 1024 * 1024;
  __bf16* WoT  = Wbase + 5 * 1024 * 1024;

  f2b_kernel<<<MROWS * DIM / 4 / 256, 256, 0, stream>>>(x, xb, MROWS * DIM / 4);
  dim3 tg(32, 32), tb(32, 8);
  transpose_f2b<<<tg, tb, 0, stream>>>(Wk,  WkT);
  transpose_f2b<<<tg, tb, 0, stream>>>(Wv,  WvT);
  transpose_f2b<<<tg, tb, 0, stream>>>(Wq,  WqT);
  transpose_f2b<<<tg, tb, 0, stream>>>(Wkm, WkmT);
  transpose_f2b<<<tg, tb, 0, stream>>>(Wqm, WqmT);
  transpose_f2b<<<tg, tb, 0, stream>>>(Wo,  WoT);

  dim3 gg(DIM / 128, MROWS / 128);   // 8 x 128 blocks
  gemm_bt<0><<<gg, 256, 0, stream>>>(xb, WkT, bk, kb,   nullptr, nullptr, nullptr);
  gemm_bt<0><<<gg, 256, 0, stream>>>(xb, WvT, bv, valb, nullptr, nullptr, nullptr);
  gemm_bt<0><<<gg, 256, 0, stream>>>(xb, WqT, bq, qb,   nullptr, nullptr, nullptr);
  // xb dead from here on
  gemm_bt<PHMODE><<<gg, 256, 0, stream>>>(kb, WkmT, bkm, kphs, basep, msc, nullptr);
  gemm_bt<PHMODE><<<gg, 256, 0, stream>>>(qb, WqmT, bqm, qphs, basep, msc, nullptr);
  // kb dead from here on (nbuf aliases it)
  phasor_ln<PT><<<NCHUNKBLKS, 256, 0, stream>>>(valb, kphs, qphs, lng, lnb, nbuf);
  gemm_bt<3><<<gg, 256, 0, stream>>>(nbuf, WoT, bo, out, nullptr, nullptr, x);
}

extern "C" void kernel_launch(void* const* d_in, const int* in_sizes, int n_in,
                              void* d_out, int out_size, void* d_ws, size_t ws_size,
                              hipStream_t stream)
{
  (void)in_sizes; (void)n_in; (void)out_size;
  const float* x     = (const float*)d_in[0];
  const float* basep = (const float*)d_in[1];
  const float* Wk    = (const float*)d_in[2];
  const float* bk    = (const float*)d_in[3];
  const float* Wv    = (const float*)d_in[4];
  const float* bv    = (const float*)d_in[5];
  const float* Wq    = (const float*)d_in[6];
  const float* bq    = (const float*)d_in[7];
  const float* Wkm   = (const float*)d_in[8];
  const float* bkm   = (const float*)d_in[9];
  const float* Wqm   = (const float*)d_in[10];
  const float* bqm   = (const float*)d_in[11];
  const float* msc   = (const float*)d_in[12];
  const float* lng   = (const float*)d_in[13];
  const float* lnb   = (const float*)d_in[14];
  const float* Wo    = (const float*)d_in[15];
  const float* bo    = (const float*)d_in[16];

  char* ws = (char*)d_ws;
  const size_t MB = 1ull << 20;

  if (ws_size >= 240 * MB) {
    // f32-phase layout (236 MB):
    //  [0,32) xb -> [0,64) kphs f32 (after xb dead)
    //  [64,96) kb   [96,128) qb   [128,160) valb   [160,224) qphs f32   [224,236) weights
    __bf16* xb   = (__bf16*)ws;
    float*  kphs = (float*)ws;
    __bf16* kb   = (__bf16*)(ws + 64 * MB);
    __bf16* qb   = (__bf16*)(ws + 96 * MB);
    __bf16* valb = (__bf16*)(ws + 128 * MB);
    float*  qphs = (float*)(ws + 160 * MB);
    __bf16* Wb   = (__bf16*)(ws + 224 * MB);
    run_pipeline<float, 2>(x, basep, Wk, bk, Wv, bv, Wq, bq, Wkm, bkm, Wqm, bqm,
                           msc, lng, lnb, Wo, bo, (float*)d_out,
                           xb, kb, qb, valb, kphs, qphs, Wb, /*nbuf=*/kb, stream);
  } else if (ws_size >= 176 * MB) {
    // bf16-phase layout (172 MB):
    //  [0,32) xb -> kphs bf16
    //  [32,64) kb  [64,96) qb  [96,128) valb  [128,160) qphs bf16  [160,172) weights
    __bf16* xb   = (__bf16*)ws;
    __bf16* kphs = (__bf16*)ws;
    __bf16* kb   = (__bf16*)(ws + 32 * MB);
    __bf16* qb   = (__bf16*)(ws + 64 * MB);
    __bf16* valb = (__bf16*)(ws + 96 * MB);
    __bf16* qphs = (__bf16*)(ws + 128 * MB);
    __bf16* Wb   = (__bf16*)(ws + 160 * MB);
    run_pipeline<__bf16, 4>(x, basep, Wk, bk, Wv, bv, Wq, bq, Wkm, bkm, Wqm, bqm,
                            msc, lng, lnb, Wo, bo, (float*)d_out,
                            xb, kb, qb, valb, kphs, qphs, Wb, /*nbuf=*/kb, stream);
  } else {
    // workspace too small for the pipeline: emit out=x as a diagnostic signature
    copyx_kernel<<<MROWS * DIM / 4 / 256, 256, 0, stream>>>(x, (float*)d_out, MROWS * DIM / 4);
  }
}

// Round 3
// 393.084 us; speedup vs baseline: 1.1317x; 1.1317x over previous
//
#include <hip/hip_runtime.h>

#define DIM 1024
#define SEQ 4096
#define MROWS 16384      // BATCH * SEQ
#define CHUNK 64
#define NCHUNKBLKS 256   // MROWS / CHUNK

typedef float  f32x4  __attribute__((ext_vector_type(4)));
typedef __bf16 bf16x8 __attribute__((ext_vector_type(8)));
typedef __bf16 bf16x4 __attribute__((ext_vector_type(4)));

// async global->LDS, 16B per lane. LDS dest is wave-uniform base + lane*16.
__device__ __forceinline__ void gld16(const void* g, void* l) {
  __builtin_amdgcn_global_load_lds((__attribute__((address_space(1))) void*)g,
                                   (__attribute__((address_space(3))) void*)l,
                                   16, 0, 0);
}

__device__ __forceinline__ f32x4 ld4f(const __bf16* p) {
  bf16x4 v = *(const bf16x4*)p;
  f32x4 r;
#pragma unroll
  for (int j = 0; j < 4; ++j) r[j] = (float)v[j];
  return r;
}

// C[M,N] = A[M,DIM] (bf16) * Bt[N,DIM]^T (bf16), fp32 accumulate.
// MODE 0: out bf16 = acc + bias
// MODE 3: out f32  = acc + bias + xres[row][col]        (final residual)
// MODE 5: out bf16 = acc * ms                           (weight combine)
// MODE 7: out bf16 = wrap(base[row%SEQ][col] + acc + bias)  (phase, wrapped to [-pi,pi])
// Tile 128x128, 4 waves. LDS both-sides XOR swizzle (chunk ^= (row>>1)&3):
// staging pre-permutes the GLOBAL source chunk (global_load_lds writes linearly),
// ds_read applies the same involution -> 2-way bank aliasing only (free).
// SWZ: XCD row-band remap for grid (8,128): each XCD owns a 16-panel row band.
template <int MODE, bool SWZ>
__global__ __launch_bounds__(256, 2)
void gemm_bt(const __bf16* __restrict__ A, const __bf16* __restrict__ Bt,
             const float* __restrict__ bias, void* __restrict__ outp,
             const float* __restrict__ basep, const float* __restrict__ mscp,
             const float* __restrict__ xres)
{
  __shared__ __bf16 As[128 * 32];   // [row][k], 64B rows, 8 KB
  __shared__ __bf16 Bs[128 * 32];
  const int tid  = threadIdx.x;
  const int lane = tid & 63;
  const int widx = tid >> 6;
  const int wr   = widx >> 1, wc = widx & 1;

  int row_t, col_t;
  if (SWZ) {
    const int b = blockIdx.y * 8 + blockIdx.x;   // grid must be (8,128)
    const int xcd = b & 7, slot = b >> 3;
    col_t = slot & 7;
    row_t = (xcd << 4) | (slot >> 3);
  } else {
    row_t = blockIdx.y; col_t = blockIdx.x;
  }
  const int row0 = row_t * 128, col0 = col_t * 128;

  // staging: lane l covers LDS bytes (widx*1024 + i*4096 + l*16)
  //  -> row = widx*16 + i*64 + (l>>2); source chunk = (l&3) ^ ((l>>3)&3)
  const int kc = ((lane & 3) ^ ((lane >> 3) & 3)) * 8;
  const __bf16* Ag = A  + (size_t)(row0 + widx * 16 + (lane >> 2)) * DIM + kc;
  const __bf16* Bg = Bt + (size_t)(col0 + widx * 16 + (lane >> 2)) * DIM + kc;
  char* AsL = (char*)As + widx * 1024;
  char* BsL = (char*)Bs + widx * 1024;

  f32x4 acc[4][4] = {};
  const bf16x8* Av = (const bf16x8*)As;
  const bf16x8* Bv = (const bf16x8*)Bs;
  const int ar = wr * 64 + (lane & 15);
  const int br = wc * 64 + (lane & 15);
  const int kg = lane >> 4;
  const int aidx = kg ^ ((ar >> 1) & 3);   // swizzled chunk (invariant under row+16)
  const int bidx = kg ^ ((br >> 1) & 3);

  for (int kt = 0; kt < DIM / 32; ++kt) {
    const __bf16* a = Ag + kt * 32;
    const __bf16* b = Bg + kt * 32;
    gld16(a,            AsL);
    gld16(a + 64 * DIM, AsL + 4096);
    gld16(b,            BsL);
    gld16(b + 64 * DIM, BsL + 4096);
    __syncthreads();
    bf16x8 af[4], bfv[4];
#pragma unroll
    for (int i = 0; i < 4; ++i) af[i]  = Av[(ar + i * 16) * 4 + aidx];
#pragma unroll
    for (int i = 0; i < 4; ++i) bfv[i] = Bv[(br + i * 16) * 4 + bidx];
#pragma unroll
    for (int mi = 0; mi < 4; ++mi)
#pragma unroll
      for (int ni = 0; ni < 4; ++ni)
        acc[mi][ni] = __builtin_amdgcn_mfma_f32_16x16x32_bf16(af[mi], bfv[ni], acc[mi][ni], 0, 0, 0);
    __syncthreads();
  }

  // C/D frag mapping (HW-verified): col = lane&15, row = (lane>>4)*4 + r
  const int ccol = col0 + wc * 64 + (lane & 15);
  const int crow = row0 + wr * 64 + kg * 4;
  float bvv[4];
  if (MODE != 5) {
#pragma unroll
    for (int ni = 0; ni < 4; ++ni) bvv[ni] = bias[ccol + ni * 16];
  }
  float ms = 0.f;
  if (MODE == 5) ms = mscp[0];
#pragma unroll
  for (int mi = 0; mi < 4; ++mi) {
#pragma unroll
    for (int ni = 0; ni < 4; ++ni) {
#pragma unroll
      for (int r = 0; r < 4; ++r) {
        const int row = crow + mi * 16 + r;
        const int col = ccol + ni * 16;
        const size_t idx = (size_t)row * DIM + col;
        if (MODE == 0) {
          ((__bf16*)outp)[idx] = (__bf16)(acc[mi][ni][r] + bvv[ni]);
        } else if (MODE == 3) {
          ((float*)outp)[idx] = acc[mi][ni][r] + bvv[ni] + xres[idx];
        } else if (MODE == 5) {
          ((__bf16*)outp)[idx] = (__bf16)(acc[mi][ni][r] * ms);
        } else {  // MODE 7
          float v = basep[(size_t)(row & (SEQ - 1)) * DIM + col] + acc[mi][ni][r] + bvv[ni];
          v -= 6.2831853f * rintf(v * 0.15915494f);   // wrap to [-pi,pi]
          ((__bf16*)outp)[idx] = (__bf16)v;
        }
      }
    }
  }
}

// Per chunk (64 rows) x full D: in-register cumsum of value*e^{i*kph},
// retrieve with qph, /sqrt(D), per-row LayerNorm, emit bf16 normed.
__global__ __launch_bounds__(256)
void phasor_ln(const __bf16* __restrict__ val, const __bf16* __restrict__ kph,
               const __bf16* __restrict__ qph, const float* __restrict__ g,
               const float* __restrict__ lb, __bf16* __restrict__ nb)
{
  const int t = threadIdx.x;
  const size_t r0 = (size_t)blockIdx.x * CHUNK;
  const int c = t * 4;
  const f32x4 gv  = ((const f32x4*)g)[t];
  const f32x4 lbv = ((const f32x4*)lb)[t];
  __shared__ float red[8];
  float mr[4] = {0.f, 0.f, 0.f, 0.f};
  float mi[4] = {0.f, 0.f, 0.f, 0.f};
  size_t base = r0 * DIM + c;
  f32x4 v  = ld4f(val + base);
  f32x4 kp = ld4f(kph + base);
  f32x4 qp = ld4f(qph + base);
  for (int r = 0; r < CHUNK; ++r) {
    const size_t nbase = base + ((r + 1 < CHUNK) ? DIM : 0);
    f32x4 nv  = ld4f(val + nbase);
    f32x4 nkp = ld4f(kph + nbase);
    f32x4 nqp = ld4f(qph + nbase);
    float ret[4];
    float s = 0.f, q = 0.f;
#pragma unroll
    for (int j = 0; j < 4; ++j) {
      float sk, ck, sq, cq;
      __sincosf(kp[j], &sk, &ck);
      mr[j] += v[j] * ck;
      mi[j] += v[j] * sk;
      __sincosf(qp[j], &sq, &cq);
      ret[j] = (mr[j] * cq + mi[j] * sq) * 0.03125f;   // 1/sqrt(1024)
      s += ret[j];
      q += ret[j] * ret[j];
    }
#pragma unroll
    for (int off = 32; off > 0; off >>= 1) {
      s += __shfl_down(s, off);
      q += __shfl_down(q, off);
    }
    if ((t & 63) == 0) { red[t >> 6] = s; red[4 + (t >> 6)] = q; }
    __syncthreads();
    const float mu   = (red[0] + red[1] + red[2] + red[3]) * (1.0f / DIM);
    const float varr = (red[4] + red[5] + red[6] + red[7]) * (1.0f / DIM) - mu * mu;
    const float rinv = rsqrtf(varr + 1e-5f);
    bf16x4 o;
#pragma unroll
    for (int j = 0; j < 4; ++j) o[j] = (__bf16)((ret[j] - mu) * rinv * gv[j] + lbv[j]);
    *(bf16x4*)(nb + base) = o;
    __syncthreads();
    base += DIM;
    v = nv; kp = nkp; qp = nqp;
  }
}

// fp32 -> bf16, 4/thread
__global__ void f2b_kernel(const float* __restrict__ in, __bf16* __restrict__ out, int n4) {
  int i = blockIdx.x * 256 + threadIdx.x;
  if (i >= n4) return;
  f32x4 vv = ((const f32x4*)in)[i];
  bf16x4 o;
#pragma unroll
  for (int j = 0; j < 4; ++j) o[j] = (__bf16)vv[j];
  ((bf16x4*)out)[i] = o;
}

// Wt[n][k] = (bf16) W[k][n]
__global__ void transpose_f2b(const float* __restrict__ W, __bf16* __restrict__ Wt) {
  __shared__ float tle[32][33];
  const int tx = threadIdx.x, ty = threadIdx.y;
  const int bx = blockIdx.x * 32, by = blockIdx.y * 32;
  for (int i = ty; i < 32; i += 8) tle[i][tx] = W[(size_t)(by + i) * DIM + bx + tx];
  __syncthreads();
  for (int i = ty; i < 32; i += 8) Wt[(size_t)(bx + i) * DIM + by + tx] = (__bf16)tle[tx][i];
}

// out[n] = (sum_k bsrc[k]*W[k][n] + badd[n]) * ms[0]   (combined bias, f32)
__global__ void biascomb_kernel(const float* __restrict__ bsrc, const float* __restrict__ W,
                                const float* __restrict__ badd, const float* __restrict__ ms,
                                float* __restrict__ out)
{
  const int n = blockIdx.x * 256 + threadIdx.x;
  float s = 0.f;
  for (int k = 0; k < DIM; ++k) s += bsrc[k] * W[(size_t)k * DIM + n];
  out[n] = (s + badd[n]) * ms[0];
}

// diagnostic fallback: out = x (absmax ~6.5 signals "workspace too small")
__global__ void copyx_kernel(const float* __restrict__ x, float* __restrict__ out, int n4) {
  int i = blockIdx.x * 256 + threadIdx.x;
  if (i >= n4) return;
  ((f32x4*)out)[i] = ((const f32x4*)x)[i];
}

extern "C" void kernel_launch(void* const* d_in, const int* in_sizes, int n_in,
                              void* d_out, int out_size, void* d_ws, size_t ws_size,
                              hipStream_t stream)
{
  (void)in_sizes; (void)n_in; (void)out_size;
  const float* x     = (const float*)d_in[0];
  const float* basep = (const float*)d_in[1];
  const float* Wk    = (const float*)d_in[2];
  const float* bk    = (const float*)d_in[3];
  const float* Wv    = (const float*)d_in[4];
  const float* bv    = (const float*)d_in[5];
  const float* Wq    = (const float*)d_in[6];
  const float* bq    = (const float*)d_in[7];
  const float* Wkm   = (const float*)d_in[8];
  const float* bkm   = (const float*)d_in[9];
  const float* Wqm   = (const float*)d_in[10];
  const float* bqm   = (const float*)d_in[11];
  const float* msc   = (const float*)d_in[12];
  const float* lng   = (const float*)d_in[13];
  const float* lnb   = (const float*)d_in[14];
  const float* Wo    = (const float*)d_in[15];
  const float* bo    = (const float*)d_in[16];
  (void)Wq; (void)bq;

  char* ws = (char*)d_ws;
  const size_t MB = 1ull << 20;
  if (ws_size < 146 * MB) {
    copyx_kernel<<<MROWS * DIM / 4 / 256, 256, 0, stream>>>(x, (float*)d_out, MROWS * DIM / 4);
    return;
  }

  // layout (144 MB + 8 KB):
  __bf16* xb    = (__bf16*)ws;              // [0,32)   x bf16; nbuf aliases after phases
  __bf16* valb  = (__bf16*)(ws +  32 * MB); // [32,64)  value bf16
  __bf16* kphb  = (__bf16*)(ws +  64 * MB); // [64,96)  key_phase bf16 (wrapped)
  __bf16* qphb  = (__bf16*)(ws +  96 * MB); // [96,128) query_phase bf16 (wrapped)
  __bf16* WvT   = (__bf16*)(ws + 128 * MB); // [128,130)
  __bf16* WoT   = (__bf16*)(ws + 130 * MB); // [130,132)
  __bf16* WkmP  = (__bf16*)(ws + 132 * MB); // [132,134) (Wk@Wkm)^T * ms, bf16
  __bf16* WqmP  = (__bf16*)(ws + 134 * MB); // [134,136)
  __bf16* TWkm  = (__bf16*)(ws + 136 * MB); // [136,138) tmp: Wkm^T
  __bf16* BWk   = (__bf16*)(ws + 138 * MB); // [138,140) tmp: bf16(Wk)
  __bf16* TWqm  = (__bf16*)(ws + 140 * MB); // [140,142) tmp: Wqm^T
  __bf16* BWq   = (__bf16*)(ws + 142 * MB); // [142,144) tmp: bf16(Wq)
  float*  bkmP  = (float*)(ws + 144 * MB);          // 4 KB
  float*  bqmP  = (float*)(ws + 144 * MB + 4096);   // 4 KB
  __bf16* nbuf  = xb;

  // --- preps ---
  f2b_kernel<<<MROWS * DIM / 4 / 256, 256, 0, stream>>>(x, xb, MROWS * DIM / 4);
  dim3 tg(32, 32), tb(32, 8);
  transpose_f2b<<<tg, tb, 0, stream>>>(Wv,  WvT);
  transpose_f2b<<<tg, tb, 0, stream>>>(Wo,  WoT);
  transpose_f2b<<<tg, tb, 0, stream>>>(Wkm, TWkm);
  transpose_f2b<<<tg, tb, 0, stream>>>(Wqm, TWqm);
  f2b_kernel<<<DIM * DIM / 4 / 256, 256, 0, stream>>>(Wk, BWk, DIM * DIM / 4);
  f2b_kernel<<<DIM * DIM / 4 / 256, 256, 0, stream>>>(Wq, BWq, DIM * DIM / 4);

  // weight combines: WkmP[n][k] = ((Wk@Wkm)[k][n]) * ms   (Bt-format for phase GEMM)
  dim3 gs(DIM / 128, DIM / 128);   // 8x8
  gemm_bt<5, false><<<gs, 256, 0, stream>>>(TWkm, BWk, nullptr, WkmP, nullptr, msc, nullptr);
  gemm_bt<5, false><<<gs, 256, 0, stream>>>(TWqm, BWq, nullptr, WqmP, nullptr, msc, nullptr);
  biascomb_kernel<<<DIM / 256, 256, 0, stream>>>(bk, Wkm, bkm, msc, bkmP);
  biascomb_kernel<<<DIM / 256, 256, 0, stream>>>(bq, Wqm, bqm, msc, bqmP);

  // --- main pipeline: 4 big GEMMs + phasor ---
  dim3 gg(DIM / 128, MROWS / 128);   // (8,128)
  gemm_bt<0, true><<<gg, 256, 0, stream>>>(xb, WvT,  bv,   valb, nullptr, nullptr, nullptr);
  gemm_bt<7, true><<<gg, 256, 0, stream>>>(xb, WkmP, bkmP, kphb, basep,   nullptr, nullptr);
  gemm_bt<7, true><<<gg, 256, 0, stream>>>(xb, WqmP, bqmP, qphb, basep,   nullptr, nullptr);
  // xb dead from here (nbuf aliases it)
  phasor_ln<<<NCHUNKBLKS, 256, 0, stream>>>(valb, kphb, qphb, lng, lnb, nbuf);
  gemm_bt<3, true><<<gg, 256, 0, stream>>>(nbuf, WoT, bo, d_out, nullptr, nullptr, x);
}